// Round 11
// baseline (480.648 us; speedup 1.0000x reference)
//
#include <hip/hip_runtime.h>
#include <cstdint>
#include <cstddef>

#define RR 32
#define R3 32768
#define NPT 32768
#define CH 240
#define CH2 480
#define NB 4
#define NTILES 2048        // NB * R3 / 64
#define Y_ELEMS 31457280   // 4*240*32768

typedef __attribute__((ext_vector_type(8))) short short8v;
typedef __attribute__((ext_vector_type(4))) short short4v;
typedef __attribute__((ext_vector_type(4))) float float4v;

union u8pack { short8v v; unsigned short u[8]; };
union u4pack { short4v v; unsigned short u[4]; };

static __device__ __forceinline__ float bf2f(unsigned short u) {
  return __uint_as_float(((unsigned int)u) << 16);
}
static __device__ __forceinline__ unsigned short f2bf(float f) {
  unsigned int u = __float_as_uint(f);
  u = (u + 0x7FFFu + ((u >> 16) & 1u)) >> 16;
  return (unsigned short)u;
}

// ---------------- merged init + coord stats ----------------
// blocks 0..3: per-batch coord mean+scale (1024 thr). blocks 4..132: init work
// (zero cnt/stats/tilectr, pack w fp32 [240][480] -> bf16 frag order).
// wfrag ushort idx: ((mg*75 + kc*5 + mL)*64 + lane)*8 + j
//   holds w[(mg*5+mL)*16 + ln][kc*32 + q*8 + j], lane = q*16+ln
__global__ __launch_bounds__(1024) void k_init(const float* __restrict__ coords,
                                               float* __restrict__ ms,
                                               int* __restrict__ cnt, float* __restrict__ stats,
                                               const float* __restrict__ w,
                                               unsigned short* __restrict__ wfrag,
                                               int* __restrict__ tilectr) {
  __shared__ float red[1024];
  __shared__ float mean[3];
  if (blockIdx.x >= 4) {
    int g = (blockIdx.x - 4) * 1024 + threadIdx.x;
    if (g == 0) *tilectr = 0;
    if (g < NB * R3) cnt[g] = 0;
    if (g < 4096) stats[g] = 0.0f;   // 8 slots x 512 (sum[256], sumsq[256])
    if (g < 14400) {
      int lane = g & 63, t = g >> 6;      // t 0..224
      int mg = t / 75, r = t % 75;
      int kc = r / 5, mL = r % 5;
      int m = mg * 5 + mL;
      int ln = lane & 15, q = lane >> 4;
      const float* src = w + (size_t)(m * 16 + ln) * CH2 + kc * 32 + q * 8;
      u8pack pk;
#pragma unroll
      for (int j = 0; j < 8; j++) pk.u[j] = f2bf(src[j]);
      *(short8v*)&wfrag[(size_t)g * 8] = pk.v;
    }
    return;
  }
  // ---- coord stats path (blocks 0..3) ----
  int b = blockIdx.x, t = threadIdx.x;
  const float4* cb4 = (const float4*)(coords + (size_t)b * 3 * NPT);
  float s[3] = {0.f, 0.f, 0.f};
  for (int i = t; i < NPT / 4; i += 1024) {
#pragma unroll
    for (int d = 0; d < 3; d++) {
      float4 v = cb4[d * (NPT / 4) + i];
      s[d] += (v.x + v.y) + (v.z + v.w);
    }
  }
  for (int d = 0; d < 3; d++) {
    red[t] = s[d]; __syncthreads();
    for (int k = 512; k > 0; k >>= 1) { if (t < k) red[t] += red[t + k]; __syncthreads(); }
    if (t == 0) mean[d] = red[0] * (1.0f / NPT);
    __syncthreads();
  }
  float m0 = mean[0], m1 = mean[1], m2 = mean[2];
  float mx = 0.f;
  for (int i = t; i < NPT / 4; i += 1024) {
    float4 x = cb4[i], y = cb4[NPT / 4 + i], z = cb4[2 * (NPT / 4) + i];
    float dx, dy, dz, n;
    dx = x.x - m0; dy = y.x - m1; dz = z.x - m2; n = dx * dx + dy * dy + dz * dz; mx = fmaxf(mx, n);
    dx = x.y - m0; dy = y.y - m1; dz = z.y - m2; n = dx * dx + dy * dy + dz * dz; mx = fmaxf(mx, n);
    dx = x.z - m0; dy = y.z - m1; dz = z.z - m2; n = dx * dx + dy * dy + dz * dz; mx = fmaxf(mx, n);
    dx = x.w - m0; dy = y.w - m1; dz = z.w - m2; n = dx * dx + dy * dy + dz * dz; mx = fmaxf(mx, n);
  }
  red[t] = mx; __syncthreads();
  for (int k = 512; k > 0; k >>= 1) { if (t < k) red[t] = fmaxf(red[t], red[t + k]); __syncthreads(); }
  if (t == 0) {
    ms[b * 4 + 0] = m0; ms[b * 4 + 1] = m1; ms[b * 4 + 2] = m2;
    ms[b * 4 + 3] = sqrtf(red[0]) * 2.0f;  // EPS_NORM = 0
  }
}

// ---------------- nc output + voxel id + histogram ----------------
__global__ void k_pos_nc(const float* __restrict__ coords, const float* __restrict__ ms,
                         float* __restrict__ ncout, int* __restrict__ pos, int* __restrict__ cnt) {
  int g = blockIdx.x * 256 + threadIdx.x;  // 0 .. NB*NPT-1
  int b = g >> 15, i = g & (NPT - 1);
  const float* cb = coords + (size_t)b * 3 * NPT;
  float scale = ms[b * 4 + 3];
  int vox[3];
#pragma unroll
  for (int d = 0; d < 3; d++) {
    float v = (cb[(size_t)d * NPT + i] - ms[b * 4 + d]) / scale + 0.5f;
    v = fminf(fmaxf(v * (float)RR, 0.0f), (float)(RR - 1));
    ncout[((size_t)(b * 3 + d)) * NPT + i] = v;
    vox[d] = (int)rintf(v);  // round-half-even, matches jnp.round
  }
  int p = (b << 15) | (vox[0] + (vox[1] << 5) + (vox[2] << 10));
  pos[g] = p;
  atomicAdd(&cnt[p], 1);
}

// ---------------- exclusive scan per batch (32768 entries) ----------------
__global__ void k_scan(const int* __restrict__ cnt, int* __restrict__ offs) {
  __shared__ int part[1024];
  int b = blockIdx.x, t = threadIdx.x;
  const int base = b * R3;
  int local[32];
  int s = 0;
#pragma unroll
  for (int j = 0; j < 32; j++) { local[j] = cnt[base + t * 32 + j]; s += local[j]; }
  part[t] = s; __syncthreads();
  for (int d = 1; d < 1024; d <<= 1) {
    int v = (t >= d) ? part[t - d] : 0;
    __syncthreads();
    part[t] += v;
    __syncthreads();
  }
  int run = (t == 0) ? 0 : part[t - 1];
#pragma unroll
  for (int j = 0; j < 32; j++) { offs[base + t * 32 + j] = run; run += local[j]; }
}

// ---------------- transpose + inline scatter: features [B,C,N] fp32 -> fts[slot][240] bf16
// slot popped inline via atomicAdd on offs (offs becomes "end" before k_fused launches).
// float4 reads (15 x 16B/thread); bf16 LDS tile (32.6 KB -> 4 blocks/CU);
// paired-point b32 LDS reads (half the LDS read instrs, 4-way banks).
__global__ __launch_bounds__(256, 4) void k_transpose3(const float* __restrict__ f,
                                                       const int* __restrict__ pos,
                                                       int* __restrict__ offs,
                                                       unsigned short* __restrict__ fts) {
  __shared__ unsigned short tile[CH * 68];  // 32,640 B
  __shared__ int slts[64];
  int p0 = blockIdx.x * 64, b = blockIdx.y;
  int t = threadIdx.x;
  if (t < 64) {
    int p = pos[b * NPT + p0 + t];
    slts[t] = atomicAdd(&offs[p], 1);      // voxel-sorted slot within batch
  }
  {
    int pg = t & 15, cq = t >> 4;        // pg: 4-point group; cq: channel phase 0..15
    const float* src = f + ((size_t)b * CH + cq) * NPT + p0 + pg * 4;
#pragma unroll
    for (int j = 0; j < 15; ++j) {
      float4 v = *(const float4*)(src + (size_t)(j * 16) * NPT);
      int c = j * 16 + cq;
      u4pack p4;
      p4.u[0] = f2bf(v.x); p4.u[1] = f2bf(v.y); p4.u[2] = f2bf(v.z); p4.u[3] = f2bf(v.w);
      *(short4v*)&tile[c * 68 + pg * 4] = p4.v;
    }
  }
  __syncthreads();
  int ch8 = t & 7;
  int pr = t >> 3;                        // point pair id 0..31 -> points {2pr, 2pr+1}
  unsigned short* dstA = fts + ((size_t)(b * NPT + slts[2 * pr])) * CH;
  unsigned short* dstB = fts + ((size_t)(b * NPT + slts[2 * pr + 1])) * CH;
#pragma unroll
  for (int i = 0; i < 4; ++i) {
    int ch = ch8 + 8 * i;                 // 16-byte chunk id, 0..29 valid
    if (ch < 30) {
      u8pack pkA, pkB;
#pragma unroll
      for (int jj = 0; jj < 8; ++jj) {
        unsigned int v = *(const unsigned int*)&tile[(ch * 8 + jj) * 68 + 2 * pr];
        pkA.u[jj] = (unsigned short)(v & 0xffffu);
        pkB.u[jj] = (unsigned short)(v >> 16);
      }
      *(short8v*)&dstA[ch * 8] = pkA.v;
      *(short8v*)&dstB[ch * 8] = pkB.v;
    }
  }
}

// ---------------- persistent fused voxel max/min + GEMM + bias + stats ----------------
// 1024 thr (16 waves = 8 m-pairs x 2 column-halves), 256 blocks (1/CU). Per-wave LDS
// read volume HALVED (2 m-tiles x 2 cg = 30 KB/wave) so total LDS traffic is unchanged
// while waves/SIMD doubles 2->4 (latency hiding for gather stalls). Register cap for a
// 1024-thr block is 512/wave -> no spill risk (the 128-cap trap doesn't apply).
// Dynamic global tile queue; LDS voxel queue (32 half-wave reducers); coop-zero fB;
// double-buffered fB; 2 barriers/iter. Round-5 algorithm otherwise unchanged.
__global__ __launch_bounds__(1024, 4) void k_fused(const int* __restrict__ cnt,
                                                   const int* __restrict__ offs,
                                                   const unsigned short* __restrict__ fts,
                                                   const unsigned short* __restrict__ wfrag,
                                                   const float* __restrict__ bias,
                                                   unsigned short* __restrict__ ybf,
                                                   float* __restrict__ gstats,
                                                   int* __restrict__ tilectr) {
  __shared__ unsigned short fB[2][4 * 15 * 512];  // 2 x 61,440 B
  __shared__ int scnt[2][64], soffs[2][64], vlist[2][64];
  __shared__ int qh[2], qm[2], tq[4];
  int tid = threadIdx.x;
  int wave = tid >> 6, lane = tid & 63;
  int mpair = wave >> 1, ch2 = wave & 1;   // m-pair 0..7, column-half 0..1
  int sub = lane >> 5, l = lane & 31;
  int ln = lane & 15, q = lane >> 4;

  // ---- w preload: register resident, 2 m-tiles per m-pair (pair 7: 1) ----
  int nmt = (mpair == 7) ? 1 : 2;
  short8v wreg[2][15];
#pragma unroll
  for (int mm = 0; mm < 2; ++mm)
    if (mm < nmt) {
      int mt = mpair * 2 + mm;
      int mg = mt / 5, mL = mt % 5;
      const unsigned short* wp = wfrag + ((size_t)(mg * 75 + mL) * 512) + lane * 8;
#pragma unroll
      for (int kc = 0; kc < 15; ++kc)
        wreg[mm][kc] = *(const short8v*)(wp + (size_t)kc * 5 * 512);
    }

  float bb[2][4];
#pragma unroll
  for (int mm = 0; mm < 2; ++mm)
    if (mm < nmt) {
      int mt = mpair * 2 + mm;
#pragma unroll
      for (int r = 0; r < 4; ++r) bb[mm][r] = bias[mt * 16 + q * 4 + r];
    }
  float sacc[2][4], sqacc[2][4];
#pragma unroll
  for (int mm = 0; mm < 2; ++mm)
#pragma unroll
    for (int r = 0; r < 4; ++r) { sacc[mm][r] = 0.f; sqacc[mm][r] = 0.f; }

  // gather lane constants (chunk t0 = l -> max half; t1 = 30+l -> min half)
  int t1c = 30 + l;
  int kc0 = l >> 2, q0 = l & 3;
  int kc1 = t1c >> 2, q1 = t1c & 3;

  auto GATHER = [&](int sb, int T) {
    unsigned short* fb = fB[sb];
    int bbase = (T >> 9) << 15;
    int qmL = qm[sb];
    while (true) {
      int p;
      if (l == 0) p = atomicAdd(&qh[sb], 1);
      p = __shfl(p, sub << 5);
      if (p >= qmL) break;
      int lv = vlist[sb][p];
      int n = scnt[sb][lv];
      int start = soffs[sb][lv] - n;      // offs is "end" after transpose's inline scatter
      int cg = lv >> 4, cc = lv & 15;
      if (l < 30) {
        const unsigned short* sp = fts + (size_t)(bbase + start) * CH + l * 8;
        int lim = (n - 1) * CH;
        float mx[8], mn[8];
#pragma unroll
        for (int k = 0; k < 8; k++) { mx[k] = -__builtin_inff(); mn[k] = __builtin_inff(); }
        for (int j = 0; j < n; j += 8) {   // fixed-depth-8 clamped: 8 loads in flight
          int base = j * CH;
          u8pack u0, u1, u2, u3, u4, u5, u6, u7;
          int o0 = base;           o0 = o0 < lim ? o0 : lim;
          int o1 = base + CH;      o1 = o1 < lim ? o1 : lim;
          int o2 = base + 2 * CH;  o2 = o2 < lim ? o2 : lim;
          int o3 = base + 3 * CH;  o3 = o3 < lim ? o3 : lim;
          int o4 = base + 4 * CH;  o4 = o4 < lim ? o4 : lim;
          int o5 = base + 5 * CH;  o5 = o5 < lim ? o5 : lim;
          int o6 = base + 6 * CH;  o6 = o6 < lim ? o6 : lim;
          int o7 = base + 7 * CH;  o7 = o7 < lim ? o7 : lim;
          u0.v = *(const short8v*)(sp + o0);
          u1.v = *(const short8v*)(sp + o1);
          u2.v = *(const short8v*)(sp + o2);
          u3.v = *(const short8v*)(sp + o3);
          u4.v = *(const short8v*)(sp + o4);
          u5.v = *(const short8v*)(sp + o5);
          u6.v = *(const short8v*)(sp + o6);
          u7.v = *(const short8v*)(sp + o7);
#pragma unroll
          for (int k = 0; k < 8; k++) {
            float a0 = bf2f(u0.u[k]), a1 = bf2f(u1.u[k]);
            float a2 = bf2f(u2.u[k]), a3 = bf2f(u3.u[k]);
            float a4 = bf2f(u4.u[k]), a5 = bf2f(u5.u[k]);
            float a6 = bf2f(u6.u[k]), a7 = bf2f(u7.u[k]);
            float hx = fmaxf(fmaxf(fmaxf(a0, a1), fmaxf(a2, a3)),
                             fmaxf(fmaxf(a4, a5), fmaxf(a6, a7)));
            float hn = fminf(fminf(fminf(a0, a1), fminf(a2, a3)),
                             fminf(fminf(a4, a5), fminf(a6, a7)));
            mx[k] = fmaxf(mx[k], hx);
            mn[k] = fminf(mn[k], hn);
          }
        }
        u8pack omx, omn;
#pragma unroll
        for (int k = 0; k < 8; k++) { omx.u[k] = f2bf(mx[k]); omn.u[k] = f2bf(mn[k]); }
        int ci0 = (q0 * 16 + cc) ^ (kc0 & 7);   // 3-bit XOR swizzle (write & read sides)
        int ci1 = (q1 * 16 + cc) ^ (kc1 & 7);
        *(short8v*)&fb[((cg * 15 + kc0) * 64 + ci0) * 8] = omx.v;
        *(short8v*)&fb[((cg * 15 + kc1) * 64 + ci1) * 8] = omn.v;
      }
    }
  };

  // ---- prologue: pop T0,T1; preload+build both slots; zero fB[0]; gather T0 ----
  if (wave == 0) {
    int t;
    if (lane == 0) t = atomicAdd(tilectr, 1);
    int T0w = __shfl(t, 0);
    if (lane == 0) t = atomicAdd(tilectr, 1);
    int T1w = __shfl(t, 0);
    if (lane == 0) { tq[0] = T0w; tq[1] = T1w; }
    int na = 0, oa = 0, nb2 = 0, ob = 0;
    if (T0w < NTILES) { na = cnt[T0w * 64 + lane]; oa = offs[T0w * 64 + lane]; }
    if (T1w < NTILES) { nb2 = cnt[T1w * 64 + lane]; ob = offs[T1w * 64 + lane]; }
    scnt[0][lane] = na; soffs[0][lane] = oa;
    {
      unsigned long long m = __ballot(na > 0);
      int pfx = __popcll(m & ((1ull << lane) - 1ull));
      if (na > 0) vlist[0][pfx] = lane;
      if (lane == 0) { qm[0] = __popcll(m); qh[0] = 0; }
    }
    scnt[1][lane] = nb2; soffs[1][lane] = ob;
    {
      unsigned long long m = __ballot(nb2 > 0);
      int pfx = __popcll(m & ((1ull << lane) - 1ull));
      if (nb2 > 0) vlist[1][pfx] = lane;
      if (lane == 0) { qm[1] = __popcll(m); qh[1] = 0; }
    }
  }
  {
    int4 z4 = {0, 0, 0, 0};
    for (int i2 = tid; i2 < 3840; i2 += 1024) ((int4*)fB[0])[i2] = z4;
  }
  __syncthreads();
  {
    int T0v = tq[0];
    if (T0v < NTILES) GATHER(0, T0v);
  }

  // ---- main loop ----
  for (int it = 0;; ++it) {
    __syncthreads();                        // barrier A: gather(T_it) done; tq visible
    int T = tq[it & 3];
    if (T >= NTILES) break;
    int cb = it & 1, nb = cb ^ 1;
    int Tn = tq[(it + 1) & 3];

    // coop zero fB[nb] (GEMM(it-1) finished with it at barrier A)
    {
      int4 z4 = {0, 0, 0, 0};
      for (int i2 = tid; i2 < 3840; i2 += 1024) ((int4*)fB[nb])[i2] = z4;
    }
    // wave0: pop T_{it+2}, issue its cnt/offs loads (consumed at end of iter)
    int n2 = 0, o2 = 0;
    if (wave == 0) {
      int t;
      if (lane == 0) t = atomicAdd(tilectr, 1);
      int Tn2 = __shfl(t, 0);
      if (lane == 0) tq[(it + 2) & 3] = Tn2;
      if (Tn2 < NTILES) { n2 = cnt[Tn2 * 64 + lane]; o2 = offs[Tn2 * 64 + lane]; }
    }
    __syncthreads();                        // barrier B: fB[nb] zeroed (cheap)

    if (Tn < NTILES) GATHER(nb, Tn);        // all waves; LDS voxel queue (32 reducers)

    // ---- GEMM tile T from fB[cb]: wave covers 2 m-tiles x 2 cg (its column half) ----
    float4v acc[2][2];
#pragma unroll
    for (int mm = 0; mm < 2; ++mm)
#pragma unroll
      for (int cg = 0; cg < 2; ++cg) acc[mm][cg] = (float4v){0.f, 0.f, 0.f, 0.f};

    const unsigned short* fbase = fB[cb];
#pragma unroll
    for (int kc = 0; kc < 15; ++kc) {
      const unsigned short* fbl = fbase + (size_t)((lane ^ (kc & 7)) * 8);
      short8v bfv[2];
#pragma unroll
      for (int cg = 0; cg < 2; ++cg)
        bfv[cg] = *(const short8v*)(fbl + (size_t)((ch2 * 2 + cg) * 15 + kc) * 512);
#pragma unroll
      for (int mm = 0; mm < 2; ++mm)
        if (mm < nmt)
#pragma unroll
          for (int cg = 0; cg < 2; ++cg)
            acc[mm][cg] = __builtin_amdgcn_mfma_f32_16x16x32_bf16(wreg[mm][kc], bfv[cg], acc[mm][cg], 0, 0, 0);
    }

    // ---- epilogue: y = acc + bias -> bf16 store; stats carried in regs ----
    int bt = T >> 9;
    int v0 = (T & 511) * 64;
    unsigned short* yb = ybf + ((size_t)bt * CH) * R3 + v0 + ch2 * 32 + ln;
#pragma unroll
    for (int mm = 0; mm < 2; ++mm)
      if (mm < nmt) {
        int mt = mpair * 2 + mm;
#pragma unroll
        for (int r = 0; r < 4; ++r) {
          int c = mt * 16 + q * 4 + r;
          unsigned short* yrow = yb + (size_t)c * R3;
          float bbv = bb[mm][r];
          float s = 0.f, sq = 0.f;
#pragma unroll
          for (int cg = 0; cg < 2; ++cg) {
            float yv = acc[mm][cg][r] + bbv;
            yrow[cg * 16] = f2bf(yv);
            s += yv; sq += yv * yv;
          }
          sacc[mm][r] += s;
          sqacc[mm][r] += sq;
        }
      }

    // wave0: build T_{it+2}'s compacted list (loads long since arrived)
    if (wave == 0) {
      int s2 = it & 1;                      // slot freed by gather(T_it) last iter
      scnt[s2][lane] = n2; soffs[s2][lane] = o2;
      unsigned long long m = __ballot(n2 > 0);
      int pfx = __popcll(m & ((1ull << lane) - 1ull));
      if (n2 > 0) vlist[s2][pfx] = lane;
      if (lane == 0) { qm[s2] = __popcll(m); qh[s2] = 0; }
    }
  }

  // ---- final stats flush: shuffle-reduce over 16 voxel-lanes, atomic per channel ----
  // (both column-half waves of an m-pair add their partial sums - atomics make it exact)
  float* gslot = gstats + (size_t)(blockIdx.x & 7) * 512;
#pragma unroll
  for (int mm = 0; mm < 2; ++mm)
    if (mm < nmt) {
      int mt = mpair * 2 + mm;
#pragma unroll
      for (int r = 0; r < 4; ++r) {
        float s = sacc[mm][r], sq = sqacc[mm][r];
#pragma unroll
        for (int off = 1; off < 16; off <<= 1) {
          s += __shfl_xor(s, off);
          sq += __shfl_xor(sq, off);
        }
        if (ln == 0) {
          int c = mt * 16 + q * 4 + r;
          atomicAdd(&gslot[c], s);
          atomicAdd(&gslot[256 + c], sq);
        }
      }
    }
}

// ---------------- apply BN (8-slot stats reduce inline) + swish, 2 chunks/thread --------
__global__ void k_apply(const unsigned short* __restrict__ ybf, float* __restrict__ out,
                        const float* __restrict__ stats, const float* __restrict__ gamma,
                        const float* __restrict__ beta) {
  int g2 = blockIdx.x * 256 + threadIdx.x;
  int g = g2 * 2;                          // even chunk id; pair never straddles a row
  int c = (g >> 12) % CH;
  const float ninv = 1.0f / (float)(NB * R3);
  float sum = 0.f, ssq = 0.f;
#pragma unroll
  for (int sl = 0; sl < 8; ++sl) {
    sum += stats[sl * 512 + c];
    ssq += stats[sl * 512 + 256 + c];
  }
  float mean = sum * ninv;
  float var = ssq * ninv - mean * mean;
  float s = gamma[c] * rsqrtf(var + 1e-5f);
  float h = beta[c] - mean * s;
  u8pack va, vb;
  va.v = *(const short8v*)(ybf + (size_t)g * 8);
  vb.v = *(const short8v*)(ybf + (size_t)(g + 1) * 8);
  float4 o0, o1, o2, o3;
  float t;
  t = bf2f(va.u[0]) * s + h; o0.x = t / (1.0f + __expf(-t));
  t = bf2f(va.u[1]) * s + h; o0.y = t / (1.0f + __expf(-t));
  t = bf2f(va.u[2]) * s + h; o0.z = t / (1.0f + __expf(-t));
  t = bf2f(va.u[3]) * s + h; o0.w = t / (1.0f + __expf(-t));
  t = bf2f(va.u[4]) * s + h; o1.x = t / (1.0f + __expf(-t));
  t = bf2f(va.u[5]) * s + h; o1.y = t / (1.0f + __expf(-t));
  t = bf2f(va.u[6]) * s + h; o1.z = t / (1.0f + __expf(-t));
  t = bf2f(va.u[7]) * s + h; o1.w = t / (1.0f + __expf(-t));
  t = bf2f(vb.u[0]) * s + h; o2.x = t / (1.0f + __expf(-t));
  t = bf2f(vb.u[1]) * s + h; o2.y = t / (1.0f + __expf(-t));
  t = bf2f(vb.u[2]) * s + h; o2.z = t / (1.0f + __expf(-t));
  t = bf2f(vb.u[3]) * s + h; o2.w = t / (1.0f + __expf(-t));
  t = bf2f(vb.u[4]) * s + h; o3.x = t / (1.0f + __expf(-t));
  t = bf2f(vb.u[5]) * s + h; o3.y = t / (1.0f + __expf(-t));
  t = bf2f(vb.u[6]) * s + h; o3.z = t / (1.0f + __expf(-t));
  t = bf2f(vb.u[7]) * s + h; o3.w = t / (1.0f + __expf(-t));
  ((float4*)out)[(size_t)g * 2]     = o0;
  ((float4*)out)[(size_t)g * 2 + 1] = o1;
  ((float4*)out)[(size_t)g * 2 + 2] = o2;
  ((float4*)out)[(size_t)g * 2 + 3] = o3;
}

extern "C" void kernel_launch(void* const* d_in, const int* in_sizes, int n_in,
                              void* d_out, int out_size, void* d_ws, size_t ws_size,
                              hipStream_t stream) {
  const float* features = (const float*)d_in[0];
  const float* coords   = (const float*)d_in[1];
  const float* w        = (const float*)d_in[2];
  const float* bias     = (const float*)d_in[3];
  const float* gamma    = (const float*)d_in[4];
  const float* beta     = (const float*)d_in[5];
  float* out = (float*)d_out;

  char* ws = (char*)d_ws;
  size_t off = 0;
  float* ms    = (float*)(ws + off); off += 256;
  int* tilectr = (int*)(ws + off);   off += 256;
  float* stats = (float*)(ws + off); off += 16384;   // 8 slots x 512 floats
  int* pos     = (int*)(ws + off);   off += (size_t)NB * NPT * 4;
  int* cnt     = (int*)(ws + off);   off += (size_t)NB * R3 * 4;
  int* offs    = (int*)(ws + off);   off += (size_t)NB * R3 * 4;
  unsigned short* wfrag = (unsigned short*)(ws + off); off += (size_t)CH * CH2 * 2;
  unsigned short* fts   = (unsigned short*)(ws + off); off += (size_t)NB * NPT * CH * 2;
  unsigned short* ybf   = (unsigned short*)(ws + off); off += (size_t)NB * R3 * CH * 2;

  float* ncout = out + Y_ELEMS;

  k_init<<<133, 1024, 0, stream>>>(coords, ms, cnt, stats, w, wfrag, tilectr);
  k_pos_nc<<<512, 256, 0, stream>>>(coords, ms, ncout, pos, cnt);
  k_scan<<<4, 1024, 0, stream>>>(cnt, offs);
  k_transpose3<<<dim3(512, 4), 256, 0, stream>>>(features, pos, offs, fts);
  k_fused<<<256, 1024, 0, stream>>>(cnt, offs, fts, wfrag, bias, ybf, stats, tilectr);
  k_apply<<<Y_ELEMS / 4096, 256, 0, stream>>>(ybf, out, stats, gamma, beta);
}

// Round 12
// 363.142 us; speedup vs baseline: 1.3236x; 1.3236x over previous
//
#include <hip/hip_runtime.h>
#include <cstdint>
#include <cstddef>

#define RR 32
#define R3 32768
#define NPT 32768
#define CH 240
#define CH2 480
#define NB 4
#define NTILES 2048        // NB * R3 / 64
#define Y_ELEMS 31457280   // 4*240*32768

typedef __attribute__((ext_vector_type(8))) short short8v;
typedef __attribute__((ext_vector_type(4))) short short4v;
typedef __attribute__((ext_vector_type(4))) float float4v;

union u8pack { short8v v; unsigned short u[8]; };
union u4pack { short4v v; unsigned short u[4]; };

static __device__ __forceinline__ float bf2f(unsigned short u) {
  return __uint_as_float(((unsigned int)u) << 16);
}
static __device__ __forceinline__ unsigned short f2bf(float f) {
  unsigned int u = __float_as_uint(f);
  u = (u + 0x7FFFu + ((u >> 16) & 1u)) >> 16;
  return (unsigned short)u;
}

// ---------------- merged init + coord stats ----------------
// blocks 0..3: per-batch coord mean+scale (1024 thr). blocks 4..132: init work
// (zero cnt/stats/tilectr, pack w fp32 [240][480] -> bf16 frag order).
// wfrag ushort idx: ((mg*75 + kc*5 + mL)*64 + lane)*8 + j
//   holds w[(mg*5+mL)*16 + ln][kc*32 + q*8 + j], lane = q*16+ln
__global__ __launch_bounds__(1024) void k_init(const float* __restrict__ coords,
                                               float* __restrict__ ms,
                                               int* __restrict__ cnt, float* __restrict__ stats,
                                               const float* __restrict__ w,
                                               unsigned short* __restrict__ wfrag,
                                               int* __restrict__ tilectr) {
  __shared__ float red[1024];
  __shared__ float mean[3];
  if (blockIdx.x >= 4) {
    int g = (blockIdx.x - 4) * 1024 + threadIdx.x;
    if (g == 0) *tilectr = 0;
    if (g < NB * R3) cnt[g] = 0;
    if (g < 4096) stats[g] = 0.0f;   // 8 slots x 512 (sum[256], sumsq[256])
    if (g < 14400) {
      int lane = g & 63, t = g >> 6;      // t 0..224
      int mg = t / 75, r = t % 75;
      int kc = r / 5, mL = r % 5;
      int m = mg * 5 + mL;
      int ln = lane & 15, q = lane >> 4;
      const float* src = w + (size_t)(m * 16 + ln) * CH2 + kc * 32 + q * 8;
      u8pack pk;
#pragma unroll
      for (int j = 0; j < 8; j++) pk.u[j] = f2bf(src[j]);
      *(short8v*)&wfrag[(size_t)g * 8] = pk.v;
    }
    return;
  }
  // ---- coord stats path (blocks 0..3) ----
  int b = blockIdx.x, t = threadIdx.x;
  const float4* cb4 = (const float4*)(coords + (size_t)b * 3 * NPT);
  float s[3] = {0.f, 0.f, 0.f};
  for (int i = t; i < NPT / 4; i += 1024) {
#pragma unroll
    for (int d = 0; d < 3; d++) {
      float4 v = cb4[d * (NPT / 4) + i];
      s[d] += (v.x + v.y) + (v.z + v.w);
    }
  }
  for (int d = 0; d < 3; d++) {
    red[t] = s[d]; __syncthreads();
    for (int k = 512; k > 0; k >>= 1) { if (t < k) red[t] += red[t + k]; __syncthreads(); }
    if (t == 0) mean[d] = red[0] * (1.0f / NPT);
    __syncthreads();
  }
  float m0 = mean[0], m1 = mean[1], m2 = mean[2];
  float mx = 0.f;
  for (int i = t; i < NPT / 4; i += 1024) {
    float4 x = cb4[i], y = cb4[NPT / 4 + i], z = cb4[2 * (NPT / 4) + i];
    float dx, dy, dz, n;
    dx = x.x - m0; dy = y.x - m1; dz = z.x - m2; n = dx * dx + dy * dy + dz * dz; mx = fmaxf(mx, n);
    dx = x.y - m0; dy = y.y - m1; dz = z.y - m2; n = dx * dx + dy * dy + dz * dz; mx = fmaxf(mx, n);
    dx = x.z - m0; dy = y.z - m1; dz = z.z - m2; n = dx * dx + dy * dy + dz * dz; mx = fmaxf(mx, n);
    dx = x.w - m0; dy = y.w - m1; dz = z.w - m2; n = dx * dx + dy * dy + dz * dz; mx = fmaxf(mx, n);
  }
  red[t] = mx; __syncthreads();
  for (int k = 512; k > 0; k >>= 1) { if (t < k) red[t] = fmaxf(red[t], red[t + k]); __syncthreads(); }
  if (t == 0) {
    ms[b * 4 + 0] = m0; ms[b * 4 + 1] = m1; ms[b * 4 + 2] = m2;
    ms[b * 4 + 3] = sqrtf(red[0]) * 2.0f;  // EPS_NORM = 0
  }
}

// ---------------- nc output + voxel id + histogram ----------------
__global__ void k_pos_nc(const float* __restrict__ coords, const float* __restrict__ ms,
                         float* __restrict__ ncout, int* __restrict__ pos, int* __restrict__ cnt) {
  int g = blockIdx.x * 256 + threadIdx.x;  // 0 .. NB*NPT-1
  int b = g >> 15, i = g & (NPT - 1);
  const float* cb = coords + (size_t)b * 3 * NPT;
  float scale = ms[b * 4 + 3];
  int vox[3];
#pragma unroll
  for (int d = 0; d < 3; d++) {
    float v = (cb[(size_t)d * NPT + i] - ms[b * 4 + d]) / scale + 0.5f;
    v = fminf(fmaxf(v * (float)RR, 0.0f), (float)(RR - 1));
    ncout[((size_t)(b * 3 + d)) * NPT + i] = v;
    vox[d] = (int)rintf(v);  // round-half-even, matches jnp.round
  }
  int p = (b << 15) | (vox[0] + (vox[1] << 5) + (vox[2] << 10));
  pos[g] = p;
  atomicAdd(&cnt[p], 1);
}

// ---------------- exclusive scan per batch (32768 entries) ----------------
__global__ void k_scan(const int* __restrict__ cnt, int* __restrict__ offs) {
  __shared__ int part[1024];
  int b = blockIdx.x, t = threadIdx.x;
  const int base = b * R3;
  int local[32];
  int s = 0;
#pragma unroll
  for (int j = 0; j < 32; j++) { local[j] = cnt[base + t * 32 + j]; s += local[j]; }
  part[t] = s; __syncthreads();
  for (int d = 1; d < 1024; d <<= 1) {
    int v = (t >= d) ? part[t - d] : 0;
    __syncthreads();
    part[t] += v;
    __syncthreads();
  }
  int run = (t == 0) ? 0 : part[t - 1];
#pragma unroll
  for (int j = 0; j < 32; j++) { offs[base + t * 32 + j] = run; run += local[j]; }
}

// ---------------- transpose + inline scatter: features [B,C,N] fp32 -> fts[slot][240] bf16
// slot popped inline via atomicAdd on offs (offs becomes "end" before k_fused launches).
// float4 reads (15 x 16B/thread); bf16 LDS tile (32.6 KB -> 4 blocks/CU);
// paired-point b32 LDS reads (half the LDS read instrs, 4-way banks).
__global__ __launch_bounds__(256, 4) void k_transpose3(const float* __restrict__ f,
                                                       const int* __restrict__ pos,
                                                       int* __restrict__ offs,
                                                       unsigned short* __restrict__ fts) {
  __shared__ unsigned short tile[CH * 68];  // 32,640 B
  __shared__ int slts[64];
  int p0 = blockIdx.x * 64, b = blockIdx.y;
  int t = threadIdx.x;
  if (t < 64) {
    int p = pos[b * NPT + p0 + t];
    slts[t] = atomicAdd(&offs[p], 1);      // voxel-sorted slot within batch
  }
  {
    int pg = t & 15, cq = t >> 4;        // pg: 4-point group; cq: channel phase 0..15
    const float* src = f + ((size_t)b * CH + cq) * NPT + p0 + pg * 4;
#pragma unroll
    for (int j = 0; j < 15; ++j) {
      float4 v = *(const float4*)(src + (size_t)(j * 16) * NPT);
      int c = j * 16 + cq;
      u4pack p4;
      p4.u[0] = f2bf(v.x); p4.u[1] = f2bf(v.y); p4.u[2] = f2bf(v.z); p4.u[3] = f2bf(v.w);
      *(short4v*)&tile[c * 68 + pg * 4] = p4.v;
    }
  }
  __syncthreads();
  int ch8 = t & 7;
  int pr = t >> 3;                        // point pair id 0..31 -> points {2pr, 2pr+1}
  unsigned short* dstA = fts + ((size_t)(b * NPT + slts[2 * pr])) * CH;
  unsigned short* dstB = fts + ((size_t)(b * NPT + slts[2 * pr + 1])) * CH;
#pragma unroll
  for (int i = 0; i < 4; ++i) {
    int ch = ch8 + 8 * i;                 // 16-byte chunk id, 0..29 valid
    if (ch < 30) {
      u8pack pkA, pkB;
#pragma unroll
      for (int jj = 0; jj < 8; ++jj) {
        unsigned int v = *(const unsigned int*)&tile[(ch * 8 + jj) * 68 + 2 * pr];
        pkA.u[jj] = (unsigned short)(v & 0xffffu);
        pkB.u[jj] = (unsigned short)(v >> 16);
      }
      *(short8v*)&dstA[ch * 8] = pkA.v;
      *(short8v*)&dstB[ch * 8] = pkB.v;
    }
  }
}

// ---------------- persistent fused voxel max/min + GEMM + bias + stats ----------------
// EXACT round-5/9/10 structure (best measured). 512 thr (8 waves), 256 blocks (1/CU),
// 256-reg cap. OCCUPANCY WALL (verified 3x): 128-reg cap spills (r2, r4); 1024-thr
// block hardware-caps 128 regs/wave and spills (r11). Do NOT graft code onto this
// kernel (r8: tail graft cost +55us via codegen perturbation). w register-resident.
// Dynamic global tile queue; LDS voxel queue; coop-zero fB; double-buffered; 2 barriers/iter.
__global__ __launch_bounds__(512, 2) void k_fused(const int* __restrict__ cnt,
                                                  const int* __restrict__ offs,
                                                  const unsigned short* __restrict__ fts,
                                                  const unsigned short* __restrict__ wfrag,
                                                  const float* __restrict__ bias,
                                                  unsigned short* __restrict__ ybf,
                                                  float* __restrict__ gstats,
                                                  int* __restrict__ tilectr) {
  __shared__ unsigned short fB[2][4 * 15 * 512];  // 2 x 61,440 B
  __shared__ int scnt[2][64], soffs[2][64], vlist[2][64];
  __shared__ int qh[2], qm[2], tq[4];
  int tid = threadIdx.x;
  int wave = tid >> 6, lane = tid & 63;
  int sub = lane >> 5, l = lane & 31;
  int ln = lane & 15, q = lane >> 4;

  // ---- w preload: register resident, 2 m-tiles per wave (wave 7: 1) ----
  int nmt = (wave == 7) ? 1 : 2;
  short8v wreg[2][15];
#pragma unroll
  for (int mm = 0; mm < 2; ++mm)
    if (mm < nmt) {
      int mt = wave * 2 + mm;
      int mg = mt / 5, mL = mt % 5;
      const unsigned short* wp = wfrag + ((size_t)(mg * 75 + mL) * 512) + lane * 8;
#pragma unroll
      for (int kc = 0; kc < 15; ++kc)
        wreg[mm][kc] = *(const short8v*)(wp + (size_t)kc * 5 * 512);
    }

  float bb[2][4];
#pragma unroll
  for (int mm = 0; mm < 2; ++mm)
    if (mm < nmt) {
      int mt = wave * 2 + mm;
#pragma unroll
      for (int r = 0; r < 4; ++r) bb[mm][r] = bias[mt * 16 + q * 4 + r];
    }
  float sacc[2][4], sqacc[2][4];
#pragma unroll
  for (int mm = 0; mm < 2; ++mm)
#pragma unroll
    for (int r = 0; r < 4; ++r) { sacc[mm][r] = 0.f; sqacc[mm][r] = 0.f; }

  // gather lane constants (chunk t0 = l -> max half; t1 = 30+l -> min half)
  int t1c = 30 + l;
  int kc0 = l >> 2, q0 = l & 3;
  int kc1 = t1c >> 2, q1 = t1c & 3;

  auto GATHER = [&](int sb, int T) {
    unsigned short* fb = fB[sb];
    int bbase = (T >> 9) << 15;
    int qmL = qm[sb];
    while (true) {
      int p;
      if (l == 0) p = atomicAdd(&qh[sb], 1);
      p = __shfl(p, sub << 5);
      if (p >= qmL) break;
      int lv = vlist[sb][p];
      int n = scnt[sb][lv];
      int start = soffs[sb][lv] - n;      // offs is "end" after transpose's inline scatter
      int cg = lv >> 4, cc = lv & 15;
      if (l < 30) {
        const unsigned short* sp = fts + (size_t)(bbase + start) * CH + l * 8;
        int lim = (n - 1) * CH;
        float mx[8], mn[8];
#pragma unroll
        for (int k = 0; k < 8; k++) { mx[k] = -__builtin_inff(); mn[k] = __builtin_inff(); }
        for (int j = 0; j < n; j += 8) {   // fixed-depth-8 clamped: 8 loads in flight
          int base = j * CH;
          u8pack u0, u1, u2, u3, u4, u5, u6, u7;
          int o0 = base;           o0 = o0 < lim ? o0 : lim;
          int o1 = base + CH;      o1 = o1 < lim ? o1 : lim;
          int o2 = base + 2 * CH;  o2 = o2 < lim ? o2 : lim;
          int o3 = base + 3 * CH;  o3 = o3 < lim ? o3 : lim;
          int o4 = base + 4 * CH;  o4 = o4 < lim ? o4 : lim;
          int o5 = base + 5 * CH;  o5 = o5 < lim ? o5 : lim;
          int o6 = base + 6 * CH;  o6 = o6 < lim ? o6 : lim;
          int o7 = base + 7 * CH;  o7 = o7 < lim ? o7 : lim;
          u0.v = *(const short8v*)(sp + o0);
          u1.v = *(const short8v*)(sp + o1);
          u2.v = *(const short8v*)(sp + o2);
          u3.v = *(const short8v*)(sp + o3);
          u4.v = *(const short8v*)(sp + o4);
          u5.v = *(const short8v*)(sp + o5);
          u6.v = *(const short8v*)(sp + o6);
          u7.v = *(const short8v*)(sp + o7);
#pragma unroll
          for (int k = 0; k < 8; k++) {
            float a0 = bf2f(u0.u[k]), a1 = bf2f(u1.u[k]);
            float a2 = bf2f(u2.u[k]), a3 = bf2f(u3.u[k]);
            float a4 = bf2f(u4.u[k]), a5 = bf2f(u5.u[k]);
            float a6 = bf2f(u6.u[k]), a7 = bf2f(u7.u[k]);
            float hx = fmaxf(fmaxf(fmaxf(a0, a1), fmaxf(a2, a3)),
                             fmaxf(fmaxf(a4, a5), fmaxf(a6, a7)));
            float hn = fminf(fminf(fminf(a0, a1), fminf(a2, a3)),
                             fminf(fminf(a4, a5), fminf(a6, a7)));
            mx[k] = fmaxf(mx[k], hx);
            mn[k] = fminf(mn[k], hn);
          }
        }
        u8pack omx, omn;
#pragma unroll
        for (int k = 0; k < 8; k++) { omx.u[k] = f2bf(mx[k]); omn.u[k] = f2bf(mn[k]); }
        int ci0 = (q0 * 16 + cc) ^ (kc0 & 7);   // 3-bit XOR swizzle (write & read sides)
        int ci1 = (q1 * 16 + cc) ^ (kc1 & 7);
        *(short8v*)&fb[((cg * 15 + kc0) * 64 + ci0) * 8] = omx.v;
        *(short8v*)&fb[((cg * 15 + kc1) * 64 + ci1) * 8] = omn.v;
      }
    }
  };

  // ---- prologue: pop T0,T1; preload+build both slots; zero fB[0]; gather T0 ----
  if (wave == 0) {
    int t;
    if (lane == 0) t = atomicAdd(tilectr, 1);
    int T0w = __shfl(t, 0);
    if (lane == 0) t = atomicAdd(tilectr, 1);
    int T1w = __shfl(t, 0);
    if (lane == 0) { tq[0] = T0w; tq[1] = T1w; }
    int na = 0, oa = 0, nb2 = 0, ob = 0;
    if (T0w < NTILES) { na = cnt[T0w * 64 + lane]; oa = offs[T0w * 64 + lane]; }
    if (T1w < NTILES) { nb2 = cnt[T1w * 64 + lane]; ob = offs[T1w * 64 + lane]; }
    scnt[0][lane] = na; soffs[0][lane] = oa;
    {
      unsigned long long m = __ballot(na > 0);
      int pfx = __popcll(m & ((1ull << lane) - 1ull));
      if (na > 0) vlist[0][pfx] = lane;
      if (lane == 0) { qm[0] = __popcll(m); qh[0] = 0; }
    }
    scnt[1][lane] = nb2; soffs[1][lane] = ob;
    {
      unsigned long long m = __ballot(nb2 > 0);
      int pfx = __popcll(m & ((1ull << lane) - 1ull));
      if (nb2 > 0) vlist[1][pfx] = lane;
      if (lane == 0) { qm[1] = __popcll(m); qh[1] = 0; }
    }
  }
  {
    int4 z4 = {0, 0, 0, 0};
    for (int i2 = tid; i2 < 3840; i2 += 512) ((int4*)fB[0])[i2] = z4;
  }
  __syncthreads();
  {
    int T0v = tq[0];
    if (T0v < NTILES) GATHER(0, T0v);
  }

  // ---- main loop ----
  for (int it = 0;; ++it) {
    __syncthreads();                        // barrier A: gather(T_it) done; tq visible
    int T = tq[it & 3];
    if (T >= NTILES) break;
    int cb = it & 1, nb = cb ^ 1;
    int Tn = tq[(it + 1) & 3];

    // coop zero fB[nb] (GEMM(it-1) finished with it at barrier A)
    {
      int4 z4 = {0, 0, 0, 0};
      for (int i2 = tid; i2 < 3840; i2 += 512) ((int4*)fB[nb])[i2] = z4;
    }
    // wave0: pop T_{it+2}, issue its cnt/offs loads (consumed at end of iter)
    int n2 = 0, o2 = 0;
    if (wave == 0) {
      int t;
      if (lane == 0) t = atomicAdd(tilectr, 1);
      int Tn2 = __shfl(t, 0);
      if (lane == 0) tq[(it + 2) & 3] = Tn2;
      if (Tn2 < NTILES) { n2 = cnt[Tn2 * 64 + lane]; o2 = offs[Tn2 * 64 + lane]; }
    }
    __syncthreads();                        // barrier B: fB[nb] zeroed (cheap)

    if (Tn < NTILES) GATHER(nb, Tn);        // all waves; LDS voxel queue

    // ---- GEMM tile T from fB[cb]: per kc 4 ds_read_b128 + 8 MFMA ----
    float4v acc[2][4];
#pragma unroll
    for (int mm = 0; mm < 2; ++mm)
#pragma unroll
      for (int cg = 0; cg < 4; ++cg) acc[mm][cg] = (float4v){0.f, 0.f, 0.f, 0.f};

    const unsigned short* fbase = fB[cb];
#pragma unroll
    for (int kc = 0; kc < 15; ++kc) {
      const unsigned short* fbl = fbase + (size_t)((lane ^ (kc & 7)) * 8);
      short8v bfv[4];
#pragma unroll
      for (int cg = 0; cg < 4; ++cg)
        bfv[cg] = *(const short8v*)(fbl + (size_t)(cg * 15 + kc) * 512);
#pragma unroll
      for (int mm = 0; mm < 2; ++mm)
        if (mm < nmt)
#pragma unroll
          for (int cg = 0; cg < 4; ++cg)
            acc[mm][cg] = __builtin_amdgcn_mfma_f32_16x16x32_bf16(wreg[mm][kc], bfv[cg], acc[mm][cg], 0, 0, 0);
    }

    // ---- epilogue: y = acc + bias -> bf16 store; stats carried in regs ----
    int bt = T >> 9;
    int v0 = (T & 511) * 64;
    unsigned short* yb = ybf + ((size_t)bt * CH) * R3 + v0 + ln;
#pragma unroll
    for (int mm = 0; mm < 2; ++mm)
      if (mm < nmt) {
        int mt = wave * 2 + mm;
#pragma unroll
        for (int r = 0; r < 4; ++r) {
          int c = mt * 16 + q * 4 + r;
          unsigned short* yrow = yb + (size_t)c * R3;
          float bbv = bb[mm][r];
          float s = 0.f, sq = 0.f;
#pragma unroll
          for (int cg = 0; cg < 4; ++cg) {
            float yv = acc[mm][cg][r] + bbv;
            yrow[cg * 16] = f2bf(yv);
            s += yv; sq += yv * yv;
          }
          sacc[mm][r] += s;
          sqacc[mm][r] += sq;
        }
      }

    // wave0: build T_{it+2}'s compacted list (loads long since arrived)
    if (wave == 0) {
      int s2 = it & 1;                      // slot freed by gather(T_it) last iter
      scnt[s2][lane] = n2; soffs[s2][lane] = o2;
      unsigned long long m = __ballot(n2 > 0);
      int pfx = __popcll(m & ((1ull << lane) - 1ull));
      if (n2 > 0) vlist[s2][pfx] = lane;
      if (lane == 0) { qm[s2] = __popcll(m); qh[s2] = 0; }
    }
  }

  // ---- final stats flush: shuffle-reduce over 16 voxel-lanes, atomic per channel ----
  float* gslot = gstats + (size_t)(blockIdx.x & 7) * 512;
#pragma unroll
  for (int mm = 0; mm < 2; ++mm)
    if (mm < nmt) {
      int mt = wave * 2 + mm;
#pragma unroll
      for (int r = 0; r < 4; ++r) {
        float s = sacc[mm][r], sq = sqacc[mm][r];
#pragma unroll
        for (int off = 1; off < 16; off <<= 1) {
          s += __shfl_xor(s, off);
          sq += __shfl_xor(sq, off);
        }
        if (ln == 0) {
          int c = mt * 16 + q * 4 + r;
          atomicAdd(&gslot[c], s);
          atomicAdd(&gslot[256 + c], sq);
        }
      }
    }
}

// ---------------- apply BN (8-slot stats reduce inline) + swish, 2 chunks/thread --------
__global__ void k_apply(const unsigned short* __restrict__ ybf, float* __restrict__ out,
                        const float* __restrict__ stats, const float* __restrict__ gamma,
                        const float* __restrict__ beta) {
  int g2 = blockIdx.x * 256 + threadIdx.x;
  int g = g2 * 2;                          // even chunk id; pair never straddles a row
  int c = (g >> 12) % CH;
  const float ninv = 1.0f / (float)(NB * R3);
  float sum = 0.f, ssq = 0.f;
#pragma unroll
  for (int sl = 0; sl < 8; ++sl) {
    sum += stats[sl * 512 + c];
    ssq += stats[sl * 512 + 256 + c];
  }
  float mean = sum * ninv;
  float var = ssq * ninv - mean * mean;
  float s = gamma[c] * rsqrtf(var + 1e-5f);
  float h = beta[c] - mean * s;
  u8pack va, vb;
  va.v = *(const short8v*)(ybf + (size_t)g * 8);
  vb.v = *(const short8v*)(ybf + (size_t)(g + 1) * 8);
  float4 o0, o1, o2, o3;
  float t;
  t = bf2f(va.u[0]) * s + h; o0.x = t / (1.0f + __expf(-t));
  t = bf2f(va.u[1]) * s + h; o0.y = t / (1.0f + __expf(-t));
  t = bf2f(va.u[2]) * s + h; o0.z = t / (1.0f + __expf(-t));
  t = bf2f(va.u[3]) * s + h; o0.w = t / (1.0f + __expf(-t));
  t = bf2f(va.u[4]) * s + h; o1.x = t / (1.0f + __expf(-t));
  t = bf2f(va.u[5]) * s + h; o1.y = t / (1.0f + __expf(-t));
  t = bf2f(va.u[6]) * s + h; o1.z = t / (1.0f + __expf(-t));
  t = bf2f(va.u[7]) * s + h; o1.w = t / (1.0f + __expf(-t));
  t = bf2f(vb.u[0]) * s + h; o2.x = t / (1.0f + __expf(-t));
  t = bf2f(vb.u[1]) * s + h; o2.y = t / (1.0f + __expf(-t));
  t = bf2f(vb.u[2]) * s + h; o2.z = t / (1.0f + __expf(-t));
  t = bf2f(vb.u[3]) * s + h; o2.w = t / (1.0f + __expf(-t));
  t = bf2f(vb.u[4]) * s + h; o3.x = t / (1.0f + __expf(-t));
  t = bf2f(vb.u[5]) * s + h; o3.y = t / (1.0f + __expf(-t));
  t = bf2f(vb.u[6]) * s + h; o3.z = t / (1.0f + __expf(-t));
  t = bf2f(vb.u[7]) * s + h; o3.w = t / (1.0f + __expf(-t));
  ((float4*)out)[(size_t)g * 2]     = o0;
  ((float4*)out)[(size_t)g * 2 + 1] = o1;
  ((float4*)out)[(size_t)g * 2 + 2] = o2;
  ((float4*)out)[(size_t)g * 2 + 3] = o3;
}

extern "C" void kernel_launch(void* const* d_in, const int* in_sizes, int n_in,
                              void* d_out, int out_size, void* d_ws, size_t ws_size,
                              hipStream_t stream) {
  const float* features = (const float*)d_in[0];
  const float* coords   = (const float*)d_in[1];
  const float* w        = (const float*)d_in[2];
  const float* bias     = (const float*)d_in[3];
  const float* gamma    = (const float*)d_in[4];
  const float* beta     = (const float*)d_in[5];
  float* out = (float*)d_out;

  char* ws = (char*)d_ws;
  size_t off = 0;
  float* ms    = (float*)(ws + off); off += 256;
  int* tilectr = (int*)(ws + off);   off += 256;
  float* stats = (float*)(ws + off); off += 16384;   // 8 slots x 512 floats
  int* pos     = (int*)(ws + off);   off += (size_t)NB * NPT * 4;
  int* cnt     = (int*)(ws + off);   off += (size_t)NB * R3 * 4;
  int* offs    = (int*)(ws + off);   off += (size_t)NB * R3 * 4;
  unsigned short* wfrag = (unsigned short*)(ws + off); off += (size_t)CH * CH2 * 2;
  unsigned short* fts   = (unsigned short*)(ws + off); off += (size_t)NB * NPT * CH * 2;
  unsigned short* ybf   = (unsigned short*)(ws + off); off += (size_t)NB * R3 * CH * 2;

  float* ncout = out + Y_ELEMS;

  k_init<<<133, 1024, 0, stream>>>(coords, ms, cnt, stats, w, wfrag, tilectr);
  k_pos_nc<<<512, 256, 0, stream>>>(coords, ms, ncout, pos, cnt);
  k_scan<<<4, 1024, 0, stream>>>(cnt, offs);
  k_transpose3<<<dim3(512, 4), 256, 0, stream>>>(features, pos, offs, fts);
  k_fused<<<256, 512, 0, stream>>>(cnt, offs, fts, wfrag, bias, ybf, stats, tilectr);
  k_apply<<<Y_ELEMS / 4096, 256, 0, stream>>>(ybf, out, stats, gamma, beta);
}